// Round 1
// baseline (778.767 us; speedup 1.0000x reference)
//
#include <hip/hip_runtime.h>

#define NN 50000
#define NE 800000
#define DD 128
#define NG 250
#define BN_EPS 1e-5f

// ---------------- CSR build ----------------

__global__ void count_k(const int* __restrict__ dst, int* __restrict__ cnt) {
    int e = blockIdx.x * 256 + threadIdx.x;
    if (e < NE) atomicAdd(&cnt[dst[e]], 1);
}

__global__ __launch_bounds__(1024) void scan_k(const int* __restrict__ cnt,
                                               int* __restrict__ rs,
                                               float* __restrict__ dis,
                                               float* __restrict__ inv) {
    __shared__ int ss[1024];
    int t = threadIdx.x;
    const int CH = (NN + 1023) / 1024;  // 49
    int lo = t * CH, hi = lo + CH;
    if (hi > NN) hi = NN;
    int s = 0;
    for (int i = lo; i < hi; i++) s += cnt[i];
    ss[t] = s;
    __syncthreads();
    for (int off = 1; off < 1024; off <<= 1) {
        int v = (t >= off) ? ss[t - off] : 0;
        __syncthreads();
        ss[t] += v;
        __syncthreads();
    }
    int run = (t > 0) ? ss[t - 1] : 0;
    for (int i = lo; i < hi; i++) {
        int ci = cnt[i];
        rs[i] = run;
        run += ci;
        float d = (float)(ci + 1);   // in-degree + self-loop
        dis[i] = 1.0f / sqrtf(d);
        inv[i] = 1.0f / d;
    }
    if (t == 1023) rs[NN] = run;
}

__global__ void fill_k(const int* __restrict__ src, const int* __restrict__ dst,
                       const int* __restrict__ rs, int* __restrict__ fc,
                       int* __restrict__ ssrc) {
    int e = blockIdx.x * 256 + threadIdx.x;
    if (e < NE) {
        int d = dst[e];
        int pos = rs[d] + atomicAdd(&fc[d], 1);
        ssrc[pos] = src[e];
    }
}

// ---------------- GEMM: H = act(A) @ W, act = BN+ReLU of prev layer (fused) ----------------
// TILE_M=32, all 128 cols per block, 256 threads, 2 blocks/CU (80KB LDS).

__global__ __launch_bounds__(256, 2) void gemm_k(const float* __restrict__ A,
                                                 const float* __restrict__ W,
                                                 const float* __restrict__ sc,
                                                 const float* __restrict__ sh,
                                                 float* __restrict__ H, int use_bn) {
    __shared__ float As[32 * 128];
    __shared__ float Ws[128 * 128];
    int tid = threadIdx.x;
    int row0 = blockIdx.x * 32;
    // stage W (16384 floats)
    {
        const float4* Wg = (const float4*)W;
        float4* Wl = (float4*)Ws;
#pragma unroll
        for (int i = 0; i < 16; i++) Wl[tid + 256 * i] = Wg[tid + 256 * i];
    }
    // stage A tile with fused BN+ReLU of previous layer
    {
        int r = tid >> 3, cg = (tid & 7) * 16;
        int grow = row0 + r;
        float4* Al = (float4*)(As + r * 128 + cg);
        if (grow < NN) {
            const float4* Ag = (const float4*)(A + (size_t)grow * DD + cg);
            if (use_bn) {
#pragma unroll
                for (int i = 0; i < 4; i++) {
                    float4 v = Ag[i];
                    float4 s4 = *(const float4*)(sc + cg + i * 4);
                    float4 t4 = *(const float4*)(sh + cg + i * 4);
                    v.x = fmaxf(fmaf(v.x, s4.x, t4.x), 0.f);
                    v.y = fmaxf(fmaf(v.y, s4.y, t4.y), 0.f);
                    v.z = fmaxf(fmaf(v.z, s4.z, t4.z), 0.f);
                    v.w = fmaxf(fmaf(v.w, s4.w, t4.w), 0.f);
                    Al[i] = v;
                }
            } else {
#pragma unroll
                for (int i = 0; i < 4; i++) Al[i] = Ag[i];
            }
        } else {
            float4 z = make_float4(0.f, 0.f, 0.f, 0.f);
#pragma unroll
            for (int i = 0; i < 4; i++) Al[i] = z;
        }
    }
    __syncthreads();
    int tx = tid & 31, ty = tid >> 5;
    float4 acc[4];
#pragma unroll
    for (int r = 0; r < 4; r++) acc[r] = make_float4(0.f, 0.f, 0.f, 0.f);
#pragma unroll 8
    for (int k = 0; k < DD; k++) {
        float4 w = *(const float4*)(Ws + k * DD + tx * 4);
#pragma unroll
        for (int r = 0; r < 4; r++) {
            float a = As[(ty + 8 * r) * DD + k];
            acc[r].x = fmaf(a, w.x, acc[r].x);
            acc[r].y = fmaf(a, w.y, acc[r].y);
            acc[r].z = fmaf(a, w.z, acc[r].z);
            acc[r].w = fmaf(a, w.w, acc[r].w);
        }
    }
#pragma unroll
    for (int r = 0; r < 4; r++) {
        int grow = row0 + ty + 8 * r;
        if (grow < NN) *(float4*)(H + (size_t)grow * DD + tx * 4) = acc[r];
    }
}

// ---------------- Gather (CSR, atomic-free) + self-loop + bias + BN stats ----------------
// One wave per node; 64 lanes cover 128 channels as float2.

__global__ __launch_bounds__(256) void gather_k(const float* __restrict__ H,
                                                const float* __restrict__ dis,
                                                const float* __restrict__ inv,
                                                const int* __restrict__ rs,
                                                const int* __restrict__ ssrc,
                                                const float* __restrict__ bias,
                                                float* __restrict__ AGG,
                                                float* __restrict__ stats) {
    __shared__ float s_sum[128], s_sq[128];
    int tid = threadIdx.x;
    if (tid < 128) { s_sum[tid] = 0.f; s_sq[tid] = 0.f; }
    __syncthreads();
    int lane = tid & 63;
    int wid = blockIdx.x * 4 + (tid >> 6);
    int nwaves = gridDim.x * 4;
    int c = lane * 2;
    float b0 = bias[c], b1 = bias[c + 1];
    float l_sum0 = 0.f, l_sum1 = 0.f, l_sq0 = 0.f, l_sq1 = 0.f;
    for (int v = wid; v < NN; v += nwaves) {
        int start = rs[v], end = rs[v + 1];
        float a0 = 0.f, a1 = 0.f;
        int e = start;
        for (; e + 2 <= end; e += 2) {  // 2-edge unroll for MLP
            int s0 = ssrc[e], s1 = ssrc[e + 1];
            float w0 = dis[s0], w1 = dis[s1];
            float2 h0 = *(const float2*)(H + (size_t)s0 * DD + c);
            float2 h1 = *(const float2*)(H + (size_t)s1 * DD + c);
            a0 += w0 * h0.x + w1 * h1.x;
            a1 += w0 * h0.y + w1 * h1.y;
        }
        if (e < end) {
            int s0 = ssrc[e];
            float w0 = dis[s0];
            float2 h0 = *(const float2*)(H + (size_t)s0 * DD + c);
            a0 += w0 * h0.x;
            a1 += w0 * h0.y;
        }
        float dv = dis[v], iv = inv[v];
        float2 hs = *(const float2*)(H + (size_t)v * DD + c);
        float o0 = fmaf(a0, dv, fmaf(hs.x, iv, b0));
        float o1 = fmaf(a1, dv, fmaf(hs.y, iv, b1));
        *(float2*)(AGG + (size_t)v * DD + c) = make_float2(o0, o1);
        l_sum0 += o0; l_sum1 += o1;
        l_sq0 += o0 * o0; l_sq1 += o1 * o1;
    }
    atomicAdd(&s_sum[c], l_sum0);
    atomicAdd(&s_sum[c + 1], l_sum1);
    atomicAdd(&s_sq[c], l_sq0);
    atomicAdd(&s_sq[c + 1], l_sq1);
    __syncthreads();
    if (tid < 128) {
        atomicAdd(&stats[tid], s_sum[tid]);
        atomicAdd(&stats[128 + tid], s_sq[tid]);
    }
}

// ---------------- BN stats -> scale/shift ----------------

__global__ void bnfix_k(const float* __restrict__ stats, const float* __restrict__ g,
                        const float* __restrict__ be, float* __restrict__ sc,
                        float* __restrict__ sh) {
    int c = threadIdx.x;
    float mean = stats[c] * (1.0f / NN);
    float var = stats[128 + c] * (1.0f / NN) - mean * mean;
    float s = g[c] / sqrtf(var + BN_EPS);
    sc[c] = s;
    sh[c] = be[c] - mean * s;
}

// ---------------- Pool: BN3+ReLU then segment-sum by (sorted) batch ----------------

__global__ __launch_bounds__(256) void pool_k(const float* __restrict__ AGG,
                                              const int* __restrict__ batch,
                                              const float* __restrict__ sc,
                                              const float* __restrict__ sh,
                                              float* __restrict__ P) {
    int lane = threadIdx.x & 63;
    int wid = blockIdx.x * 4 + (threadIdx.x >> 6);
    int nw = gridDim.x * 4;
    int c = lane * 2;
    float sc0 = sc[c], sc1 = sc[c + 1], sh0 = sh[c], sh1 = sh[c + 1];
    int chunk = (NN + nw - 1) / nw;
    int v0 = wid * chunk, v1 = v0 + chunk;
    if (v1 > NN) v1 = NN;
    if (v0 >= NN) return;
    int curb = batch[v0];
    float acc0 = 0.f, acc1 = 0.f;
    for (int v = v0; v < v1; v++) {
        int b = batch[v];
        if (b != curb) {
            atomicAdd(&P[curb * 128 + c], acc0);
            atomicAdd(&P[curb * 128 + c + 1], acc1);
            acc0 = 0.f; acc1 = 0.f; curb = b;
        }
        float2 hv = *(const float2*)(AGG + (size_t)v * DD + c);
        acc0 += fmaxf(fmaf(hv.x, sc0, sh0), 0.f);
        acc1 += fmaxf(fmaf(hv.y, sc1, sh1), 0.f);
    }
    atomicAdd(&P[curb * 128 + c], acc0);
    atomicAdd(&P[curb * 128 + c + 1], acc1);
}

// ---------------- Head: relu(P @ Wm1 + bm1) @ Wm2 + bm2 ----------------

__global__ __launch_bounds__(128) void head_k(const float* __restrict__ P,
                                              const float* __restrict__ Wm1,
                                              const float* __restrict__ bm1,
                                              const float* __restrict__ Wm2,
                                              const float* __restrict__ bm2,
                                              float* __restrict__ OUT) {
    __shared__ float prow[128];
    __shared__ float red[128];
    int g = blockIdx.x, t = threadIdx.x;
    prow[t] = P[g * 128 + t];
    __syncthreads();
    float acc = bm1[t];
#pragma unroll 8
    for (int i = 0; i < 128; i++) acc = fmaf(prow[i], Wm1[i * 128 + t], acc);
    red[t] = fmaxf(acc, 0.f) * Wm2[t];
    __syncthreads();
    for (int off = 64; off > 0; off >>= 1) {
        if (t < off) red[t] += red[t + off];
        __syncthreads();
    }
    if (t == 0) OUT[g] = red[0] + bm2[0];
}

// ---------------- Launch ----------------

extern "C" void kernel_launch(void* const* d_in, const int* in_sizes, int n_in,
                              void* d_out, int out_size, void* d_ws, size_t ws_size,
                              hipStream_t stream) {
    const float* x   = (const float*)d_in[0];
    const int*  ei   = (const int*)d_in[1];
    const int*  batch= (const int*)d_in[2];
    const float* W1  = (const float*)d_in[3];
    const float* b1  = (const float*)d_in[4];
    const float* g1  = (const float*)d_in[5];
    const float* be1 = (const float*)d_in[6];
    const float* W2  = (const float*)d_in[7];
    const float* b2  = (const float*)d_in[8];
    const float* g2  = (const float*)d_in[9];
    const float* be2 = (const float*)d_in[10];
    const float* W3  = (const float*)d_in[11];
    const float* b3  = (const float*)d_in[12];
    const float* g3  = (const float*)d_in[13];
    const float* be3 = (const float*)d_in[14];
    const float* Wm1 = (const float*)d_in[15];
    const float* bm1 = (const float*)d_in[16];
    const float* Wm2 = (const float*)d_in[17];
    const float* bm2 = (const float*)d_in[18];
    float* out = (float*)d_out;

    char* ws = (char*)d_ws;
    size_t off = 0;
    auto alloc = [&](size_t bytes) -> void* {
        void* p = ws + off;
        off = (off + bytes + 255) & ~(size_t)255;
        return p;
    };
    int*   cnt   = (int*)alloc((size_t)NN * 4);
    int*   rs    = (int*)alloc((size_t)(NN + 1) * 4);
    int*   fc    = (int*)alloc((size_t)NN * 4);
    float* dis   = (float*)alloc((size_t)NN * 4);
    float* inv   = (float*)alloc((size_t)NN * 4);
    int*   ssrc  = (int*)alloc((size_t)NE * 4);
    float* h     = (float*)alloc((size_t)NN * DD * 4);
    float* agg   = (float*)alloc((size_t)NN * DD * 4);
    float* stats = (float*)alloc(3 * 256 * 4);
    float* scb   = (float*)alloc(3 * 128 * 4);
    float* shb   = (float*)alloc(3 * 128 * 4);
    float* p     = (float*)alloc((size_t)NG * DD * 4);

    const int* srcI = ei;
    const int* dstI = ei + NE;

    hipMemsetAsync(cnt, 0, (size_t)NN * 4, stream);
    hipMemsetAsync(fc, 0, (size_t)NN * 4, stream);
    hipMemsetAsync(stats, 0, 3 * 256 * 4, stream);
    hipMemsetAsync(p, 0, (size_t)NG * DD * 4, stream);

    count_k<<<(NE + 255) / 256, 256, 0, stream>>>(dstI, cnt);
    scan_k<<<1, 1024, 0, stream>>>(cnt, rs, dis, inv);
    fill_k<<<(NE + 255) / 256, 256, 0, stream>>>(srcI, dstI, rs, fc, ssrc);

    const int GB = (NN + 31) / 32;

    // Layer 1
    gemm_k<<<GB, 256, 0, stream>>>(x, W1, nullptr, nullptr, h, 0);
    gather_k<<<2048, 256, 0, stream>>>(h, dis, inv, rs, ssrc, b1, agg, stats);
    bnfix_k<<<1, 128, 0, stream>>>(stats, g1, be1, scb, shb);

    // Layer 2
    gemm_k<<<GB, 256, 0, stream>>>(agg, W2, scb, shb, h, 1);
    gather_k<<<2048, 256, 0, stream>>>(h, dis, inv, rs, ssrc, b2, agg, stats + 256);
    bnfix_k<<<1, 128, 0, stream>>>(stats + 256, g2, be2, scb + 128, shb + 128);

    // Layer 3
    gemm_k<<<GB, 256, 0, stream>>>(agg, W3, scb + 128, shb + 128, h, 1);
    gather_k<<<2048, 256, 0, stream>>>(h, dis, inv, rs, ssrc, b3, agg, stats + 512);
    bnfix_k<<<1, 128, 0, stream>>>(stats + 512, g3, be3, scb + 256, shb + 256);

    // Pool + head
    pool_k<<<128, 256, 0, stream>>>(agg, batch, scb + 256, shb + 256, p);
    head_k<<<NG, 128, 0, stream>>>(p, Wm1, bm1, Wm2, bm2, out);
}

// Round 2
// 654.529 us; speedup vs baseline: 1.1898x; 1.1898x over previous
//
#include <hip/hip_runtime.h>

#define NN 50000
#define NE 800000
#define DD 128
#define NG 250
#define BN_EPS 1e-5f

#define SCAN_B 256
#define SCAN_CH ((NN + SCAN_B - 1) / SCAN_B)   // 196

// ---------------- CSR build ----------------

__global__ void count_k(const int* __restrict__ dst, int* __restrict__ cnt) {
    int e = blockIdx.x * 256 + threadIdx.x;
    if (e < NE) atomicAdd(&cnt[dst[e]], 1);
}

// Phase A: per-chunk sums (coalesced)
__global__ __launch_bounds__(256) void sum_k(const int* __restrict__ cnt,
                                             int* __restrict__ bsum) {
    __shared__ int red[256];
    int b = blockIdx.x, t = threadIdx.x;
    int lo = b * SCAN_CH, hi = lo + SCAN_CH;
    if (hi > NN) hi = NN;
    int s = 0;
    for (int i = lo + t; i < hi; i += 256) s += cnt[i];
    red[t] = s;
    __syncthreads();
    for (int off = 128; off > 0; off >>= 1) {
        if (t < off) red[t] += red[t + off];
        __syncthreads();
    }
    if (t == 0) bsum[b] = red[0];
}

// Phase B: exclusive scan of the 256 block sums
__global__ __launch_bounds__(256) void bscan_k(const int* __restrict__ bsum,
                                               int* __restrict__ boff,
                                               int* __restrict__ rs) {
    __shared__ int ss[256];
    int t = threadIdx.x;
    int v = bsum[t];
    ss[t] = v;
    __syncthreads();
    for (int off = 1; off < 256; off <<= 1) {
        int u = (t >= off) ? ss[t - off] : 0;
        __syncthreads();
        ss[t] += u;
        __syncthreads();
    }
    boff[t] = ss[t] - v;   // exclusive
    if (t == 0) rs[NN] = NE;
}

// Phase C: local inclusive scan per chunk -> rs, dis, inv
__global__ __launch_bounds__(256) void cscan_k(const int* __restrict__ cnt,
                                               const int* __restrict__ boff,
                                               int* __restrict__ rs,
                                               float* __restrict__ dis,
                                               float* __restrict__ inv) {
    __shared__ int ss[256];
    int b = blockIdx.x, t = threadIdx.x;
    int lo = b * SCAN_CH;
    int i = lo + t;
    int v = (t < SCAN_CH && i < NN) ? cnt[i] : 0;
    ss[t] = v;
    __syncthreads();
    for (int off = 1; off < 256; off <<= 1) {
        int u = (t >= off) ? ss[t - off] : 0;
        __syncthreads();
        ss[t] += u;
        __syncthreads();
    }
    if (t < SCAN_CH && i < NN) {
        rs[i] = ss[t] - v + boff[b];
        float d = (float)(v + 1);   // in-degree + self-loop
        dis[i] = 1.0f / sqrtf(d);
        inv[i] = 1.0f / d;
    }
}

__global__ void fill_k(const int* __restrict__ src, const int* __restrict__ dst,
                       const int* __restrict__ rs, int* __restrict__ fc,
                       int* __restrict__ ssrc) {
    int e = blockIdx.x * 256 + threadIdx.x;
    if (e < NE) {
        int d = dst[e];
        int pos = rs[d] + atomicAdd(&fc[d], 1);
        ssrc[pos] = src[e];
    }
}

// ---------------- GEMM: H = act(A) @ W, act = BN+ReLU of prev layer (fused) ----------------

__global__ __launch_bounds__(256, 2) void gemm_k(const float* __restrict__ A,
                                                 const float* __restrict__ W,
                                                 const float* __restrict__ sc,
                                                 const float* __restrict__ sh,
                                                 float* __restrict__ H, int use_bn) {
    __shared__ float As[32 * 128];
    __shared__ float Ws[128 * 128];
    int tid = threadIdx.x;
    int row0 = blockIdx.x * 32;
    {
        const float4* Wg = (const float4*)W;
        float4* Wl = (float4*)Ws;
#pragma unroll
        for (int i = 0; i < 16; i++) Wl[tid + 256 * i] = Wg[tid + 256 * i];
    }
    {
        int r = tid >> 3, cg = (tid & 7) * 16;
        int grow = row0 + r;
        float4* Al = (float4*)(As + r * 128 + cg);
        if (grow < NN) {
            const float4* Ag = (const float4*)(A + (size_t)grow * DD + cg);
            if (use_bn) {
#pragma unroll
                for (int i = 0; i < 4; i++) {
                    float4 v = Ag[i];
                    float4 s4 = *(const float4*)(sc + cg + i * 4);
                    float4 t4 = *(const float4*)(sh + cg + i * 4);
                    v.x = fmaxf(fmaf(v.x, s4.x, t4.x), 0.f);
                    v.y = fmaxf(fmaf(v.y, s4.y, t4.y), 0.f);
                    v.z = fmaxf(fmaf(v.z, s4.z, t4.z), 0.f);
                    v.w = fmaxf(fmaf(v.w, s4.w, t4.w), 0.f);
                    Al[i] = v;
                }
            } else {
#pragma unroll
                for (int i = 0; i < 4; i++) Al[i] = Ag[i];
            }
        } else {
            float4 z = make_float4(0.f, 0.f, 0.f, 0.f);
#pragma unroll
            for (int i = 0; i < 4; i++) Al[i] = z;
        }
    }
    __syncthreads();
    int tx = tid & 31, ty = tid >> 5;
    float4 acc[4];
#pragma unroll
    for (int r = 0; r < 4; r++) acc[r] = make_float4(0.f, 0.f, 0.f, 0.f);
#pragma unroll 8
    for (int k = 0; k < DD; k++) {
        float4 w = *(const float4*)(Ws + k * DD + tx * 4);
#pragma unroll
        for (int r = 0; r < 4; r++) {
            float a = As[(ty + 8 * r) * DD + k];
            acc[r].x = fmaf(a, w.x, acc[r].x);
            acc[r].y = fmaf(a, w.y, acc[r].y);
            acc[r].z = fmaf(a, w.z, acc[r].z);
            acc[r].w = fmaf(a, w.w, acc[r].w);
        }
    }
#pragma unroll
    for (int r = 0; r < 4; r++) {
        int grow = row0 + ty + 8 * r;
        if (grow < NN) *(float4*)(H + (size_t)grow * DD + tx * 4) = acc[r];
    }
}

// ---------------- Gather (CSR, atomic-free) + self-loop + bias + BN stats ----------------

__global__ __launch_bounds__(256) void gather_k(const float* __restrict__ H,
                                                const float* __restrict__ dis,
                                                const float* __restrict__ inv,
                                                const int* __restrict__ rs,
                                                const int* __restrict__ ssrc,
                                                const float* __restrict__ bias,
                                                float* __restrict__ AGG,
                                                float* __restrict__ stats) {
    __shared__ float s_sum[128], s_sq[128];
    int tid = threadIdx.x;
    if (tid < 128) { s_sum[tid] = 0.f; s_sq[tid] = 0.f; }
    __syncthreads();
    int lane = tid & 63;
    int wid = blockIdx.x * 4 + (tid >> 6);
    int nwaves = gridDim.x * 4;
    int c = lane * 2;
    float b0 = bias[c], b1 = bias[c + 1];
    float l_sum0 = 0.f, l_sum1 = 0.f, l_sq0 = 0.f, l_sq1 = 0.f;
    for (int v = wid; v < NN; v += nwaves) {
        int start = rs[v], end = rs[v + 1];
        float a0 = 0.f, a1 = 0.f;
        int e = start;
        for (; e + 2 <= end; e += 2) {
            int s0 = ssrc[e], s1 = ssrc[e + 1];
            float w0 = dis[s0], w1 = dis[s1];
            float2 h0 = *(const float2*)(H + (size_t)s0 * DD + c);
            float2 h1 = *(const float2*)(H + (size_t)s1 * DD + c);
            a0 += w0 * h0.x + w1 * h1.x;
            a1 += w0 * h0.y + w1 * h1.y;
        }
        if (e < end) {
            int s0 = ssrc[e];
            float w0 = dis[s0];
            float2 h0 = *(const float2*)(H + (size_t)s0 * DD + c);
            a0 += w0 * h0.x;
            a1 += w0 * h0.y;
        }
        float dv = dis[v], iv = inv[v];
        float2 hs = *(const float2*)(H + (size_t)v * DD + c);
        float o0 = fmaf(a0, dv, fmaf(hs.x, iv, b0));
        float o1 = fmaf(a1, dv, fmaf(hs.y, iv, b1));
        *(float2*)(AGG + (size_t)v * DD + c) = make_float2(o0, o1);
        l_sum0 += o0; l_sum1 += o1;
        l_sq0 += o0 * o0; l_sq1 += o1 * o1;
    }
    atomicAdd(&s_sum[c], l_sum0);
    atomicAdd(&s_sum[c + 1], l_sum1);
    atomicAdd(&s_sq[c], l_sq0);
    atomicAdd(&s_sq[c + 1], l_sq1);
    __syncthreads();
    if (tid < 128) {
        atomicAdd(&stats[tid], s_sum[tid]);
        atomicAdd(&stats[128 + tid], s_sq[tid]);
    }
}

// ---------------- BN stats -> scale/shift ----------------

__global__ void bnfix_k(const float* __restrict__ stats, const float* __restrict__ g,
                        const float* __restrict__ be, float* __restrict__ sc,
                        float* __restrict__ sh) {
    int c = threadIdx.x;
    float mean = stats[c] * (1.0f / NN);
    float var = stats[128 + c] * (1.0f / NN) - mean * mean;
    float s = g[c] / sqrtf(var + BN_EPS);
    sc[c] = s;
    sh[c] = be[c] - mean * s;
}

// ---------------- Pool ----------------

__global__ __launch_bounds__(256) void pool_k(const float* __restrict__ AGG,
                                              const int* __restrict__ batch,
                                              const float* __restrict__ sc,
                                              const float* __restrict__ sh,
                                              float* __restrict__ P) {
    int lane = threadIdx.x & 63;
    int wid = blockIdx.x * 4 + (threadIdx.x >> 6);
    int nw = gridDim.x * 4;
    int c = lane * 2;
    float sc0 = sc[c], sc1 = sc[c + 1], sh0 = sh[c], sh1 = sh[c + 1];
    int chunk = (NN + nw - 1) / nw;
    int v0 = wid * chunk, v1 = v0 + chunk;
    if (v1 > NN) v1 = NN;
    if (v0 >= NN) return;
    int curb = batch[v0];
    float acc0 = 0.f, acc1 = 0.f;
    for (int v = v0; v < v1; v++) {
        int b = batch[v];
        if (b != curb) {
            atomicAdd(&P[curb * 128 + c], acc0);
            atomicAdd(&P[curb * 128 + c + 1], acc1);
            acc0 = 0.f; acc1 = 0.f; curb = b;
        }
        float2 hv = *(const float2*)(AGG + (size_t)v * DD + c);
        acc0 += fmaxf(fmaf(hv.x, sc0, sh0), 0.f);
        acc1 += fmaxf(fmaf(hv.y, sc1, sh1), 0.f);
    }
    atomicAdd(&P[curb * 128 + c], acc0);
    atomicAdd(&P[curb * 128 + c + 1], acc1);
}

// ---------------- Head ----------------

__global__ __launch_bounds__(128) void head_k(const float* __restrict__ P,
                                              const float* __restrict__ Wm1,
                                              const float* __restrict__ bm1,
                                              const float* __restrict__ Wm2,
                                              const float* __restrict__ bm2,
                                              float* __restrict__ OUT) {
    __shared__ float prow[128];
    __shared__ float red[128];
    int g = blockIdx.x, t = threadIdx.x;
    prow[t] = P[g * 128 + t];
    __syncthreads();
    float acc = bm1[t];
#pragma unroll 8
    for (int i = 0; i < 128; i++) acc = fmaf(prow[i], Wm1[i * 128 + t], acc);
    red[t] = fmaxf(acc, 0.f) * Wm2[t];
    __syncthreads();
    for (int off = 64; off > 0; off >>= 1) {
        if (t < off) red[t] += red[t + off];
        __syncthreads();
    }
    if (t == 0) OUT[g] = red[0] + bm2[0];
}

// ---------------- Launch ----------------

extern "C" void kernel_launch(void* const* d_in, const int* in_sizes, int n_in,
                              void* d_out, int out_size, void* d_ws, size_t ws_size,
                              hipStream_t stream) {
    const float* x   = (const float*)d_in[0];
    const int*  ei   = (const int*)d_in[1];
    const int*  batch= (const int*)d_in[2];
    const float* W1  = (const float*)d_in[3];
    const float* b1  = (const float*)d_in[4];
    const float* g1  = (const float*)d_in[5];
    const float* be1 = (const float*)d_in[6];
    const float* W2  = (const float*)d_in[7];
    const float* b2  = (const float*)d_in[8];
    const float* g2  = (const float*)d_in[9];
    const float* be2 = (const float*)d_in[10];
    const float* W3  = (const float*)d_in[11];
    const float* b3  = (const float*)d_in[12];
    const float* g3  = (const float*)d_in[13];
    const float* be3 = (const float*)d_in[14];
    const float* Wm1 = (const float*)d_in[15];
    const float* bm1 = (const float*)d_in[16];
    const float* Wm2 = (const float*)d_in[17];
    const float* bm2 = (const float*)d_in[18];
    float* out = (float*)d_out;

    char* ws = (char*)d_ws;
    size_t off = 0;
    auto alloc = [&](size_t bytes) -> void* {
        void* p = ws + off;
        off = (off + bytes + 255) & ~(size_t)255;
        return p;
    };
    int*   cnt   = (int*)alloc((size_t)NN * 4);
    int*   rs    = (int*)alloc((size_t)(NN + 1) * 4);
    int*   fc    = (int*)alloc((size_t)NN * 4);
    float* dis   = (float*)alloc((size_t)NN * 4);
    float* inv   = (float*)alloc((size_t)NN * 4);
    int*   ssrc  = (int*)alloc((size_t)NE * 4);
    float* h     = (float*)alloc((size_t)NN * DD * 4);
    float* agg   = (float*)alloc((size_t)NN * DD * 4);
    float* stats = (float*)alloc(3 * 256 * 4);
    float* scb   = (float*)alloc(3 * 128 * 4);
    float* shb   = (float*)alloc(3 * 128 * 4);
    float* p     = (float*)alloc((size_t)NG * DD * 4);
    int*   bsum  = (int*)alloc(SCAN_B * 4);
    int*   boff  = (int*)alloc(SCAN_B * 4);

    const int* srcI = ei;
    const int* dstI = ei + NE;

    hipMemsetAsync(cnt, 0, (size_t)NN * 4, stream);
    hipMemsetAsync(fc, 0, (size_t)NN * 4, stream);
    hipMemsetAsync(stats, 0, 3 * 256 * 4, stream);
    hipMemsetAsync(p, 0, (size_t)NG * DD * 4, stream);

    count_k<<<(NE + 255) / 256, 256, 0, stream>>>(dstI, cnt);
    sum_k<<<SCAN_B, 256, 0, stream>>>(cnt, bsum);
    bscan_k<<<1, 256, 0, stream>>>(bsum, boff, rs);
    cscan_k<<<SCAN_B, 256, 0, stream>>>(cnt, boff, rs, dis, inv);
    fill_k<<<(NE + 255) / 256, 256, 0, stream>>>(srcI, dstI, rs, fc, ssrc);

    const int GB = (NN + 31) / 32;

    // Layer 1
    gemm_k<<<GB, 256, 0, stream>>>(x, W1, nullptr, nullptr, h, 0);
    gather_k<<<2048, 256, 0, stream>>>(h, dis, inv, rs, ssrc, b1, agg, stats);
    bnfix_k<<<1, 128, 0, stream>>>(stats, g1, be1, scb, shb);

    // Layer 2
    gemm_k<<<GB, 256, 0, stream>>>(agg, W2, scb, shb, h, 1);
    gather_k<<<2048, 256, 0, stream>>>(h, dis, inv, rs, ssrc, b2, agg, stats + 256);
    bnfix_k<<<1, 128, 0, stream>>>(stats + 256, g2, be2, scb + 128, shb + 128);

    // Layer 3
    gemm_k<<<GB, 256, 0, stream>>>(agg, W3, scb + 128, shb + 128, h, 1);
    gather_k<<<2048, 256, 0, stream>>>(h, dis, inv, rs, ssrc, b3, agg, stats + 512);
    bnfix_k<<<1, 128, 0, stream>>>(stats + 512, g3, be3, scb + 256, shb + 256);

    // Pool + head
    pool_k<<<128, 256, 0, stream>>>(agg, batch, scb + 256, shb + 256, p);
    head_k<<<NG, 128, 0, stream>>>(p, Wm1, bm1, Wm2, bm2, out);
}

// Round 3
// 583.951 us; speedup vs baseline: 1.3336x; 1.1209x over previous
//
#include <hip/hip_runtime.h>

#define NN 50000
#define NE 800000
#define DD 128
#define NG 250
#define BN_EPS 1e-5f

#define SCAN_B 256
#define SCAN_CH ((NN + SCAN_B - 1) / SCAN_B)   // 196

typedef unsigned short u16;

__device__ inline u16 f2bf(float f) {
    union { float f; unsigned u; } c;
    c.f = f;
    unsigned r = c.u + 0x7fffu + ((c.u >> 16) & 1u);  // RTNE
    return (u16)(r >> 16);
}
__device__ inline float bf_lo(unsigned u) {
    union { unsigned u; float f; } c;
    c.u = u << 16;
    return c.f;
}
__device__ inline float bf_hi(unsigned u) {
    union { unsigned u; float f; } c;
    c.u = u & 0xffff0000u;
    return c.f;
}

// ---------------- CSR build ----------------

__global__ void count_k(const int* __restrict__ dst, int* __restrict__ cnt) {
    int e = blockIdx.x * 256 + threadIdx.x;
    if (e < NE) atomicAdd(&cnt[dst[e]], 1);
}

__global__ __launch_bounds__(256) void sum_k(const int* __restrict__ cnt,
                                             int* __restrict__ bsum) {
    __shared__ int red[256];
    int b = blockIdx.x, t = threadIdx.x;
    int lo = b * SCAN_CH, hi = lo + SCAN_CH;
    if (hi > NN) hi = NN;
    int s = 0;
    for (int i = lo + t; i < hi; i += 256) s += cnt[i];
    red[t] = s;
    __syncthreads();
    for (int off = 128; off > 0; off >>= 1) {
        if (t < off) red[t] += red[t + off];
        __syncthreads();
    }
    if (t == 0) bsum[b] = red[0];
}

__global__ __launch_bounds__(256) void bscan_k(const int* __restrict__ bsum,
                                               int* __restrict__ boff,
                                               int* __restrict__ rs) {
    __shared__ int ss[256];
    int t = threadIdx.x;
    int v = bsum[t];
    ss[t] = v;
    __syncthreads();
    for (int off = 1; off < 256; off <<= 1) {
        int u = (t >= off) ? ss[t - off] : 0;
        __syncthreads();
        ss[t] += u;
        __syncthreads();
    }
    boff[t] = ss[t] - v;
    if (t == 0) rs[NN] = NE;
}

__global__ __launch_bounds__(256) void cscan_k(const int* __restrict__ cnt,
                                               const int* __restrict__ boff,
                                               int* __restrict__ rs,
                                               float* __restrict__ dis,
                                               float* __restrict__ inv) {
    __shared__ int ss[256];
    int b = blockIdx.x, t = threadIdx.x;
    int lo = b * SCAN_CH;
    int i = lo + t;
    int v = (t < SCAN_CH && i < NN) ? cnt[i] : 0;
    ss[t] = v;
    __syncthreads();
    for (int off = 1; off < 256; off <<= 1) {
        int u = (t >= off) ? ss[t - off] : 0;
        __syncthreads();
        ss[t] += u;
        __syncthreads();
    }
    if (t < SCAN_CH && i < NN) {
        rs[i] = ss[t] - v + boff[b];
        float d = (float)(v + 1);
        dis[i] = 1.0f / sqrtf(d);
        inv[i] = 1.0f / d;
    }
}

__global__ void fill_k(const int* __restrict__ src, const int* __restrict__ dst,
                       const int* __restrict__ rs, int* __restrict__ fc,
                       int* __restrict__ ssrc) {
    int e = blockIdx.x * 256 + threadIdx.x;
    if (e < NE) {
        int d = dst[e];
        int pos = rs[d] + atomicAdd(&fc[d], 1);
        ssrc[pos] = src[e];
    }
}

// ---------------- GEMM: HB(bf16) = act(A) @ W ----------------

__global__ __launch_bounds__(256, 2) void gemm_k(const float* __restrict__ A,
                                                 const float* __restrict__ W,
                                                 const float* __restrict__ sc,
                                                 const float* __restrict__ sh,
                                                 u16* __restrict__ HB, int use_bn) {
    __shared__ float As[32 * 128];
    __shared__ float Ws[128 * 128];
    int tid = threadIdx.x;
    int row0 = blockIdx.x * 32;
    {
        const float4* Wg = (const float4*)W;
        float4* Wl = (float4*)Ws;
#pragma unroll
        for (int i = 0; i < 16; i++) Wl[tid + 256 * i] = Wg[tid + 256 * i];
    }
    {
        int r = tid >> 3, cg = (tid & 7) * 16;
        int grow = row0 + r;
        float4* Al = (float4*)(As + r * 128 + cg);
        if (grow < NN) {
            const float4* Ag = (const float4*)(A + (size_t)grow * DD + cg);
            if (use_bn) {
#pragma unroll
                for (int i = 0; i < 4; i++) {
                    float4 v = Ag[i];
                    float4 s4 = *(const float4*)(sc + cg + i * 4);
                    float4 t4 = *(const float4*)(sh + cg + i * 4);
                    v.x = fmaxf(fmaf(v.x, s4.x, t4.x), 0.f);
                    v.y = fmaxf(fmaf(v.y, s4.y, t4.y), 0.f);
                    v.z = fmaxf(fmaf(v.z, s4.z, t4.z), 0.f);
                    v.w = fmaxf(fmaf(v.w, s4.w, t4.w), 0.f);
                    Al[i] = v;
                }
            } else {
#pragma unroll
                for (int i = 0; i < 4; i++) Al[i] = Ag[i];
            }
        } else {
            float4 z = make_float4(0.f, 0.f, 0.f, 0.f);
#pragma unroll
            for (int i = 0; i < 4; i++) Al[i] = z;
        }
    }
    __syncthreads();
    int tx = tid & 31, ty = tid >> 5;
    float4 acc[4];
#pragma unroll
    for (int r = 0; r < 4; r++) acc[r] = make_float4(0.f, 0.f, 0.f, 0.f);
#pragma unroll 8
    for (int k = 0; k < DD; k++) {
        float4 w = *(const float4*)(Ws + k * DD + tx * 4);
#pragma unroll
        for (int r = 0; r < 4; r++) {
            float a = As[(ty + 8 * r) * DD + k];
            acc[r].x = fmaf(a, w.x, acc[r].x);
            acc[r].y = fmaf(a, w.y, acc[r].y);
            acc[r].z = fmaf(a, w.z, acc[r].z);
            acc[r].w = fmaf(a, w.w, acc[r].w);
        }
    }
#pragma unroll
    for (int r = 0; r < 4; r++) {
        int grow = row0 + ty + 8 * r;
        if (grow < NN) {
            ushort4 o;
            o.x = f2bf(acc[r].x);
            o.y = f2bf(acc[r].y);
            o.z = f2bf(acc[r].z);
            o.w = f2bf(acc[r].w);
            *(ushort4*)(HB + (size_t)grow * DD + tx * 4) = o;
        }
    }
}

// ---------------- Gather (bf16 rows) + self-loop + bias + BN stats ----------------

__global__ __launch_bounds__(256) void gather_k(const u16* __restrict__ HB,
                                                const float* __restrict__ dis,
                                                const float* __restrict__ inv,
                                                const int* __restrict__ rs,
                                                const int* __restrict__ ssrc,
                                                const float* __restrict__ bias,
                                                float* __restrict__ AGG,
                                                float* __restrict__ stats) {
    __shared__ float s_sum[128], s_sq[128];
    int tid = threadIdx.x;
    if (tid < 128) { s_sum[tid] = 0.f; s_sq[tid] = 0.f; }
    __syncthreads();
    int lane = tid & 63;
    int wid = blockIdx.x * 4 + (tid >> 6);
    int nwaves = gridDim.x * 4;
    int c = lane * 2;
    float b0 = bias[c], b1 = bias[c + 1];
    float l_sum0 = 0.f, l_sum1 = 0.f, l_sq0 = 0.f, l_sq1 = 0.f;
    for (int v = wid; v < NN; v += nwaves) {
        int start = rs[v], end = rs[v + 1];
        float a0 = 0.f, a1 = 0.f;
        int e = start;
        for (; e + 4 <= end; e += 4) {
            int s0 = ssrc[e], s1 = ssrc[e + 1], s2 = ssrc[e + 2], s3 = ssrc[e + 3];
            unsigned r0 = *(const unsigned*)(HB + (size_t)s0 * DD + c);
            unsigned r1 = *(const unsigned*)(HB + (size_t)s1 * DD + c);
            unsigned r2 = *(const unsigned*)(HB + (size_t)s2 * DD + c);
            unsigned r3 = *(const unsigned*)(HB + (size_t)s3 * DD + c);
            float w0 = dis[s0], w1 = dis[s1], w2 = dis[s2], w3 = dis[s3];
            a0 += w0 * bf_lo(r0) + w1 * bf_lo(r1) + w2 * bf_lo(r2) + w3 * bf_lo(r3);
            a1 += w0 * bf_hi(r0) + w1 * bf_hi(r1) + w2 * bf_hi(r2) + w3 * bf_hi(r3);
        }
        for (; e < end; e++) {
            int s0 = ssrc[e];
            unsigned r0 = *(const unsigned*)(HB + (size_t)s0 * DD + c);
            float w0 = dis[s0];
            a0 += w0 * bf_lo(r0);
            a1 += w0 * bf_hi(r0);
        }
        float dv = dis[v], iv = inv[v];
        unsigned rs_ = *(const unsigned*)(HB + (size_t)v * DD + c);
        float o0 = fmaf(a0, dv, fmaf(bf_lo(rs_), iv, b0));
        float o1 = fmaf(a1, dv, fmaf(bf_hi(rs_), iv, b1));
        *(float2*)(AGG + (size_t)v * DD + c) = make_float2(o0, o1);
        l_sum0 += o0; l_sum1 += o1;
        l_sq0 += o0 * o0; l_sq1 += o1 * o1;
    }
    atomicAdd(&s_sum[c], l_sum0);
    atomicAdd(&s_sum[c + 1], l_sum1);
    atomicAdd(&s_sq[c], l_sq0);
    atomicAdd(&s_sq[c + 1], l_sq1);
    __syncthreads();
    if (tid < 128) {
        atomicAdd(&stats[tid], s_sum[tid]);
        atomicAdd(&stats[128 + tid], s_sq[tid]);
    }
}

// ---------------- BN stats -> scale/shift ----------------

__global__ void bnfix_k(const float* __restrict__ stats, const float* __restrict__ g,
                        const float* __restrict__ be, float* __restrict__ sc,
                        float* __restrict__ sh) {
    int c = threadIdx.x;
    float mean = stats[c] * (1.0f / NN);
    float var = stats[128 + c] * (1.0f / NN) - mean * mean;
    float s = g[c] / sqrtf(var + BN_EPS);
    sc[c] = s;
    sh[c] = be[c] - mean * s;
}

// ---------------- Pool ----------------

__global__ __launch_bounds__(256) void pool_k(const float* __restrict__ AGG,
                                              const int* __restrict__ batch,
                                              const float* __restrict__ sc,
                                              const float* __restrict__ sh,
                                              float* __restrict__ P) {
    int lane = threadIdx.x & 63;
    int wid = blockIdx.x * 4 + (threadIdx.x >> 6);
    int nw = gridDim.x * 4;
    int c = lane * 2;
    float sc0 = sc[c], sc1 = sc[c + 1], sh0 = sh[c], sh1 = sh[c + 1];
    int chunk = (NN + nw - 1) / nw;
    int v0 = wid * chunk, v1 = v0 + chunk;
    if (v1 > NN) v1 = NN;
    if (v0 >= NN) return;
    int curb = batch[v0];
    float acc0 = 0.f, acc1 = 0.f;
    for (int v = v0; v < v1; v++) {
        int b = batch[v];
        if (b != curb) {
            atomicAdd(&P[curb * 128 + c], acc0);
            atomicAdd(&P[curb * 128 + c + 1], acc1);
            acc0 = 0.f; acc1 = 0.f; curb = b;
        }
        float2 hv = *(const float2*)(AGG + (size_t)v * DD + c);
        acc0 += fmaxf(fmaf(hv.x, sc0, sh0), 0.f);
        acc1 += fmaxf(fmaf(hv.y, sc1, sh1), 0.f);
    }
    atomicAdd(&P[curb * 128 + c], acc0);
    atomicAdd(&P[curb * 128 + c + 1], acc1);
}

// ---------------- Head ----------------

__global__ __launch_bounds__(128) void head_k(const float* __restrict__ P,
                                              const float* __restrict__ Wm1,
                                              const float* __restrict__ bm1,
                                              const float* __restrict__ Wm2,
                                              const float* __restrict__ bm2,
                                              float* __restrict__ OUT) {
    __shared__ float prow[128];
    __shared__ float red[128];
    int g = blockIdx.x, t = threadIdx.x;
    prow[t] = P[g * 128 + t];
    __syncthreads();
    float acc = bm1[t];
#pragma unroll 8
    for (int i = 0; i < 128; i++) acc = fmaf(prow[i], Wm1[i * 128 + t], acc);
    red[t] = fmaxf(acc, 0.f) * Wm2[t];
    __syncthreads();
    for (int off = 64; off > 0; off >>= 1) {
        if (t < off) red[t] += red[t + off];
        __syncthreads();
    }
    if (t == 0) OUT[g] = red[0] + bm2[0];
}

// ---------------- Launch ----------------

extern "C" void kernel_launch(void* const* d_in, const int* in_sizes, int n_in,
                              void* d_out, int out_size, void* d_ws, size_t ws_size,
                              hipStream_t stream) {
    const float* x   = (const float*)d_in[0];
    const int*  ei   = (const int*)d_in[1];
    const int*  batch= (const int*)d_in[2];
    const float* W1  = (const float*)d_in[3];
    const float* b1  = (const float*)d_in[4];
    const float* g1  = (const float*)d_in[5];
    const float* be1 = (const float*)d_in[6];
    const float* W2  = (const float*)d_in[7];
    const float* b2  = (const float*)d_in[8];
    const float* g2  = (const float*)d_in[9];
    const float* be2 = (const float*)d_in[10];
    const float* W3  = (const float*)d_in[11];
    const float* b3  = (const float*)d_in[12];
    const float* g3  = (const float*)d_in[13];
    const float* be3 = (const float*)d_in[14];
    const float* Wm1 = (const float*)d_in[15];
    const float* bm1 = (const float*)d_in[16];
    const float* Wm2 = (const float*)d_in[17];
    const float* bm2 = (const float*)d_in[18];
    float* out = (float*)d_out;

    char* ws = (char*)d_ws;
    size_t off = 0;
    auto alloc = [&](size_t bytes) -> void* {
        void* p = ws + off;
        off = (off + bytes + 255) & ~(size_t)255;
        return p;
    };
    int*   cnt   = (int*)alloc((size_t)NN * 4);
    int*   rs    = (int*)alloc((size_t)(NN + 1) * 4);
    int*   fc    = (int*)alloc((size_t)NN * 4);
    float* dis   = (float*)alloc((size_t)NN * 4);
    float* inv   = (float*)alloc((size_t)NN * 4);
    int*   ssrc  = (int*)alloc((size_t)NE * 4);
    u16*   hb    = (u16*)alloc((size_t)NN * DD * 2);
    float* agg   = (float*)alloc((size_t)NN * DD * 4);
    float* stats = (float*)alloc(3 * 256 * 4);
    float* scb   = (float*)alloc(3 * 128 * 4);
    float* shb   = (float*)alloc(3 * 128 * 4);
    float* p     = (float*)alloc((size_t)NG * DD * 4);
    int*   bsum  = (int*)alloc(SCAN_B * 4);
    int*   boff  = (int*)alloc(SCAN_B * 4);

    const int* srcI = ei;
    const int* dstI = ei + NE;

    hipMemsetAsync(cnt, 0, (size_t)NN * 4, stream);
    hipMemsetAsync(fc, 0, (size_t)NN * 4, stream);
    hipMemsetAsync(stats, 0, 3 * 256 * 4, stream);
    hipMemsetAsync(p, 0, (size_t)NG * DD * 4, stream);

    count_k<<<(NE + 255) / 256, 256, 0, stream>>>(dstI, cnt);
    sum_k<<<SCAN_B, 256, 0, stream>>>(cnt, bsum);
    bscan_k<<<1, 256, 0, stream>>>(bsum, boff, rs);
    cscan_k<<<SCAN_B, 256, 0, stream>>>(cnt, boff, rs, dis, inv);
    fill_k<<<(NE + 255) / 256, 256, 0, stream>>>(srcI, dstI, rs, fc, ssrc);

    const int GB = (NN + 31) / 32;

    // Layer 1
    gemm_k<<<GB, 256, 0, stream>>>(x, W1, nullptr, nullptr, hb, 0);
    gather_k<<<2048, 256, 0, stream>>>(hb, dis, inv, rs, ssrc, b1, agg, stats);
    bnfix_k<<<1, 128, 0, stream>>>(stats, g1, be1, scb, shb);

    // Layer 2
    gemm_k<<<GB, 256, 0, stream>>>(agg, W2, scb, shb, hb, 1);
    gather_k<<<2048, 256, 0, stream>>>(hb, dis, inv, rs, ssrc, b2, agg, stats + 256);
    bnfix_k<<<1, 128, 0, stream>>>(stats + 256, g2, be2, scb + 128, shb + 128);

    // Layer 3
    gemm_k<<<GB, 256, 0, stream>>>(agg, W3, scb + 128, shb + 128, hb, 1);
    gather_k<<<2048, 256, 0, stream>>>(hb, dis, inv, rs, ssrc, b3, agg, stats + 512);
    bnfix_k<<<1, 128, 0, stream>>>(stats + 512, g3, be3, scb + 256, shb + 256);

    // Pool + head
    pool_k<<<128, 256, 0, stream>>>(agg, batch, scb + 256, shb + 256, p);
    head_k<<<NG, 128, 0, stream>>>(p, Wm1, bm1, Wm2, bm2, out);
}

// Round 4
// 571.465 us; speedup vs baseline: 1.3628x; 1.0218x over previous
//
#include <hip/hip_runtime.h>

#define NN 50000
#define NE 800000
#define DD 128
#define NG 250
#define BN_EPS 1e-5f

#define SCAN_B 256
#define SCAN_CH ((NN + SCAN_B - 1) / SCAN_B)   // 196

typedef unsigned short u16;

__device__ inline u16 f2bf(float f) {
    union { float f; unsigned u; } c;
    c.f = f;
    unsigned r = c.u + 0x7fffu + ((c.u >> 16) & 1u);  // RTNE
    return (u16)(r >> 16);
}
__device__ inline float bf_lo(unsigned u) {
    union { unsigned u; float f; } c;
    c.u = u << 16;
    return c.f;
}
__device__ inline float bf_hi(unsigned u) {
    union { unsigned u; float f; } c;
    c.u = u & 0xffff0000u;
    return c.f;
}

// ---------------- CSR build ----------------

__global__ void count_k(const int* __restrict__ dst, int* __restrict__ cnt) {
    int e = blockIdx.x * 256 + threadIdx.x;
    if (e < NE) atomicAdd(&cnt[dst[e]], 1);
}

__global__ __launch_bounds__(256) void sum_k(const int* __restrict__ cnt,
                                             int* __restrict__ bsum) {
    __shared__ int red[256];
    int b = blockIdx.x, t = threadIdx.x;
    int lo = b * SCAN_CH, hi = lo + SCAN_CH;
    if (hi > NN) hi = NN;
    int s = 0;
    for (int i = lo + t; i < hi; i += 256) s += cnt[i];
    red[t] = s;
    __syncthreads();
    for (int off = 128; off > 0; off >>= 1) {
        if (t < off) red[t] += red[t + off];
        __syncthreads();
    }
    if (t == 0) bsum[b] = red[0];
}

__global__ __launch_bounds__(256) void bscan_k(const int* __restrict__ bsum,
                                               int* __restrict__ boff,
                                               int* __restrict__ rs) {
    __shared__ int ss[256];
    int t = threadIdx.x;
    int v = bsum[t];
    ss[t] = v;
    __syncthreads();
    for (int off = 1; off < 256; off <<= 1) {
        int u = (t >= off) ? ss[t - off] : 0;
        __syncthreads();
        ss[t] += u;
        __syncthreads();
    }
    boff[t] = ss[t] - v;
    if (t == 0) rs[NN] = NE;
}

__global__ __launch_bounds__(256) void cscan_k(const int* __restrict__ cnt,
                                               const int* __restrict__ boff,
                                               int* __restrict__ rs,
                                               float* __restrict__ dis) {
    __shared__ int ss[256];
    int b = blockIdx.x, t = threadIdx.x;
    int lo = b * SCAN_CH;
    int i = lo + t;
    int v = (t < SCAN_CH && i < NN) ? cnt[i] : 0;
    ss[t] = v;
    __syncthreads();
    for (int off = 1; off < 256; off <<= 1) {
        int u = (t >= off) ? ss[t - off] : 0;
        __syncthreads();
        ss[t] += u;
        __syncthreads();
    }
    if (t < SCAN_CH && i < NN) {
        rs[i] = ss[t] - v + boff[b];
        float d = (float)(v + 1);
        dis[i] = 1.0f / sqrtf(d);
    }
}

__global__ void fill_k(const int* __restrict__ src, const int* __restrict__ dst,
                       const int* __restrict__ rs, int* __restrict__ fc,
                       int* __restrict__ ssrc) {
    int e = blockIdx.x * 256 + threadIdx.x;
    if (e < NE) {
        int d = dst[e];
        int pos = rs[d] + atomicAdd(&fc[d], 1);
        ssrc[pos] = src[e];
    }
}

// ---------------- GEMM: HB(bf16) = dis[row] * (act(A) @ W) ----------------

__global__ __launch_bounds__(256, 2) void gemm_k(const float* __restrict__ A,
                                                 const float* __restrict__ W,
                                                 const float* __restrict__ sc,
                                                 const float* __restrict__ sh,
                                                 const float* __restrict__ dis,
                                                 u16* __restrict__ HB, int use_bn) {
    __shared__ float As[32 * 128];
    __shared__ float Ws[128 * 128];
    int tid = threadIdx.x;
    int row0 = blockIdx.x * 32;
    {
        const float4* Wg = (const float4*)W;
        float4* Wl = (float4*)Ws;
#pragma unroll
        for (int i = 0; i < 16; i++) Wl[tid + 256 * i] = Wg[tid + 256 * i];
    }
    {
        int r = tid >> 3, cg = (tid & 7) * 16;
        int grow = row0 + r;
        float4* Al = (float4*)(As + r * 128 + cg);
        if (grow < NN) {
            const float4* Ag = (const float4*)(A + (size_t)grow * DD + cg);
            if (use_bn) {
#pragma unroll
                for (int i = 0; i < 4; i++) {
                    float4 v = Ag[i];
                    float4 s4 = *(const float4*)(sc + cg + i * 4);
                    float4 t4 = *(const float4*)(sh + cg + i * 4);
                    v.x = fmaxf(fmaf(v.x, s4.x, t4.x), 0.f);
                    v.y = fmaxf(fmaf(v.y, s4.y, t4.y), 0.f);
                    v.z = fmaxf(fmaf(v.z, s4.z, t4.z), 0.f);
                    v.w = fmaxf(fmaf(v.w, s4.w, t4.w), 0.f);
                    Al[i] = v;
                }
            } else {
#pragma unroll
                for (int i = 0; i < 4; i++) Al[i] = Ag[i];
            }
        } else {
            float4 z = make_float4(0.f, 0.f, 0.f, 0.f);
#pragma unroll
            for (int i = 0; i < 4; i++) Al[i] = z;
        }
    }
    __syncthreads();
    int tx = tid & 31, ty = tid >> 5;
    float4 acc[4];
#pragma unroll
    for (int r = 0; r < 4; r++) acc[r] = make_float4(0.f, 0.f, 0.f, 0.f);
#pragma unroll 8
    for (int k = 0; k < DD; k++) {
        float4 w = *(const float4*)(Ws + k * DD + tx * 4);
#pragma unroll
        for (int r = 0; r < 4; r++) {
            float a = As[(ty + 8 * r) * DD + k];
            acc[r].x = fmaf(a, w.x, acc[r].x);
            acc[r].y = fmaf(a, w.y, acc[r].y);
            acc[r].z = fmaf(a, w.z, acc[r].z);
            acc[r].w = fmaf(a, w.w, acc[r].w);
        }
    }
#pragma unroll
    for (int r = 0; r < 4; r++) {
        int grow = row0 + ty + 8 * r;
        if (grow < NN) {
            float dv = dis[grow];
            ushort4 o;
            o.x = f2bf(acc[r].x * dv);
            o.y = f2bf(acc[r].y * dv);
            o.z = f2bf(acc[r].z * dv);
            o.w = f2bf(acc[r].w * dv);
            *(ushort4*)(HB + (size_t)grow * DD + tx * 4) = o;
        }
    }
}

// ---------------- Gather (pre-scaled bf16 rows) + self-loop + bias + BN stats ----------------
// out[v] = dis[v] * (sum_{s in N(v)} HB[s] + HB[v]) + bias

__global__ __launch_bounds__(256) void gather_k(const u16* __restrict__ HB,
                                                const float* __restrict__ dis,
                                                const int* __restrict__ rs,
                                                const int* __restrict__ ssrc,
                                                const float* __restrict__ bias,
                                                float* __restrict__ AGG,
                                                float* __restrict__ stats) {
    __shared__ float s_sum[128], s_sq[128];
    int tid = threadIdx.x;
    if (tid < 128) { s_sum[tid] = 0.f; s_sq[tid] = 0.f; }
    __syncthreads();
    int lane = tid & 63;
    int wid = blockIdx.x * 4 + (tid >> 6);
    int nwaves = gridDim.x * 4;
    int c = lane * 2;
    float b0 = bias[c], b1 = bias[c + 1];
    float l_sum0 = 0.f, l_sum1 = 0.f, l_sq0 = 0.f, l_sq1 = 0.f;
    for (int v = wid; v < NN; v += nwaves) {
        int start = rs[v], end = rs[v + 1];
        float a0 = 0.f, a1 = 0.f;
        for (int base = start; base < end; base += 64) {
            int rem = end - base;
            int cnt = rem < 64 ? rem : 64;
            int myidx = (lane < cnt) ? ssrc[base + lane] : 0;
            int j = 0;
            for (; j + 8 <= cnt; j += 8) {
                int s0 = __shfl(myidx, j);
                int s1 = __shfl(myidx, j + 1);
                int s2 = __shfl(myidx, j + 2);
                int s3 = __shfl(myidx, j + 3);
                int s4 = __shfl(myidx, j + 4);
                int s5 = __shfl(myidx, j + 5);
                int s6 = __shfl(myidx, j + 6);
                int s7 = __shfl(myidx, j + 7);
                unsigned r0 = *(const unsigned*)(HB + (size_t)s0 * DD + c);
                unsigned r1 = *(const unsigned*)(HB + (size_t)s1 * DD + c);
                unsigned r2 = *(const unsigned*)(HB + (size_t)s2 * DD + c);
                unsigned r3 = *(const unsigned*)(HB + (size_t)s3 * DD + c);
                unsigned r4 = *(const unsigned*)(HB + (size_t)s4 * DD + c);
                unsigned r5 = *(const unsigned*)(HB + (size_t)s5 * DD + c);
                unsigned r6 = *(const unsigned*)(HB + (size_t)s6 * DD + c);
                unsigned r7 = *(const unsigned*)(HB + (size_t)s7 * DD + c);
                a0 += bf_lo(r0) + bf_lo(r1) + bf_lo(r2) + bf_lo(r3)
                    + bf_lo(r4) + bf_lo(r5) + bf_lo(r6) + bf_lo(r7);
                a1 += bf_hi(r0) + bf_hi(r1) + bf_hi(r2) + bf_hi(r3)
                    + bf_hi(r4) + bf_hi(r5) + bf_hi(r6) + bf_hi(r7);
            }
            for (; j < cnt; j++) {
                int s0 = __shfl(myidx, j);
                unsigned r0 = *(const unsigned*)(HB + (size_t)s0 * DD + c);
                a0 += bf_lo(r0);
                a1 += bf_hi(r0);
            }
        }
        unsigned rsf = *(const unsigned*)(HB + (size_t)v * DD + c);
        float dv = dis[v];
        float o0 = fmaf(a0 + bf_lo(rsf), dv, b0);
        float o1 = fmaf(a1 + bf_hi(rsf), dv, b1);
        *(float2*)(AGG + (size_t)v * DD + c) = make_float2(o0, o1);
        l_sum0 += o0; l_sum1 += o1;
        l_sq0 += o0 * o0; l_sq1 += o1 * o1;
    }
    atomicAdd(&s_sum[c], l_sum0);
    atomicAdd(&s_sum[c + 1], l_sum1);
    atomicAdd(&s_sq[c], l_sq0);
    atomicAdd(&s_sq[c + 1], l_sq1);
    __syncthreads();
    if (tid < 128) {
        atomicAdd(&stats[tid], s_sum[tid]);
        atomicAdd(&stats[128 + tid], s_sq[tid]);
    }
}

// ---------------- BN stats -> scale/shift ----------------

__global__ void bnfix_k(const float* __restrict__ stats, const float* __restrict__ g,
                        const float* __restrict__ be, float* __restrict__ sc,
                        float* __restrict__ sh) {
    int c = threadIdx.x;
    float mean = stats[c] * (1.0f / NN);
    float var = stats[128 + c] * (1.0f / NN) - mean * mean;
    float s = g[c] / sqrtf(var + BN_EPS);
    sc[c] = s;
    sh[c] = be[c] - mean * s;
}

// ---------------- Pool ----------------

__global__ __launch_bounds__(256) void pool_k(const float* __restrict__ AGG,
                                              const int* __restrict__ batch,
                                              const float* __restrict__ sc,
                                              const float* __restrict__ sh,
                                              float* __restrict__ P) {
    int lane = threadIdx.x & 63;
    int wid = blockIdx.x * 4 + (threadIdx.x >> 6);
    int nw = gridDim.x * 4;
    int c = lane * 2;
    float sc0 = sc[c], sc1 = sc[c + 1], sh0 = sh[c], sh1 = sh[c + 1];
    int chunk = (NN + nw - 1) / nw;
    int v0 = wid * chunk, v1 = v0 + chunk;
    if (v1 > NN) v1 = NN;
    if (v0 >= NN) return;
    int curb = batch[v0];
    float acc0 = 0.f, acc1 = 0.f;
    for (int v = v0; v < v1; v++) {
        int b = batch[v];
        if (b != curb) {
            atomicAdd(&P[curb * 128 + c], acc0);
            atomicAdd(&P[curb * 128 + c + 1], acc1);
            acc0 = 0.f; acc1 = 0.f; curb = b;
        }
        float2 hv = *(const float2*)(AGG + (size_t)v * DD + c);
        acc0 += fmaxf(fmaf(hv.x, sc0, sh0), 0.f);
        acc1 += fmaxf(fmaf(hv.y, sc1, sh1), 0.f);
    }
    atomicAdd(&P[curb * 128 + c], acc0);
    atomicAdd(&P[curb * 128 + c + 1], acc1);
}

// ---------------- Head ----------------

__global__ __launch_bounds__(128) void head_k(const float* __restrict__ P,
                                              const float* __restrict__ Wm1,
                                              const float* __restrict__ bm1,
                                              const float* __restrict__ Wm2,
                                              const float* __restrict__ bm2,
                                              float* __restrict__ OUT) {
    __shared__ float prow[128];
    __shared__ float red[128];
    int g = blockIdx.x, t = threadIdx.x;
    prow[t] = P[g * 128 + t];
    __syncthreads();
    float acc = bm1[t];
#pragma unroll 8
    for (int i = 0; i < 128; i++) acc = fmaf(prow[i], Wm1[i * 128 + t], acc);
    red[t] = fmaxf(acc, 0.f) * Wm2[t];
    __syncthreads();
    for (int off = 64; off > 0; off >>= 1) {
        if (t < off) red[t] += red[t + off];
        __syncthreads();
    }
    if (t == 0) OUT[g] = red[0] + bm2[0];
}

// ---------------- Launch ----------------

extern "C" void kernel_launch(void* const* d_in, const int* in_sizes, int n_in,
                              void* d_out, int out_size, void* d_ws, size_t ws_size,
                              hipStream_t stream) {
    const float* x   = (const float*)d_in[0];
    const int*  ei   = (const int*)d_in[1];
    const int*  batch= (const int*)d_in[2];
    const float* W1  = (const float*)d_in[3];
    const float* b1  = (const float*)d_in[4];
    const float* g1  = (const float*)d_in[5];
    const float* be1 = (const float*)d_in[6];
    const float* W2  = (const float*)d_in[7];
    const float* b2  = (const float*)d_in[8];
    const float* g2  = (const float*)d_in[9];
    const float* be2 = (const float*)d_in[10];
    const float* W3  = (const float*)d_in[11];
    const float* b3  = (const float*)d_in[12];
    const float* g3  = (const float*)d_in[13];
    const float* be3 = (const float*)d_in[14];
    const float* Wm1 = (const float*)d_in[15];
    const float* bm1 = (const float*)d_in[16];
    const float* Wm2 = (const float*)d_in[17];
    const float* bm2 = (const float*)d_in[18];
    float* out = (float*)d_out;

    char* ws = (char*)d_ws;
    size_t off = 0;
    auto alloc = [&](size_t bytes) -> void* {
        void* p = ws + off;
        off = (off + bytes + 255) & ~(size_t)255;
        return p;
    };
    int*   cnt   = (int*)alloc((size_t)NN * 4);
    int*   rs    = (int*)alloc((size_t)(NN + 1) * 4);
    int*   fc    = (int*)alloc((size_t)NN * 4);
    float* dis   = (float*)alloc((size_t)NN * 4);
    int*   ssrc  = (int*)alloc((size_t)NE * 4);
    u16*   hb    = (u16*)alloc((size_t)NN * DD * 2);
    float* agg   = (float*)alloc((size_t)NN * DD * 4);
    float* stats = (float*)alloc(3 * 256 * 4);
    float* scb   = (float*)alloc(3 * 128 * 4);
    float* shb   = (float*)alloc(3 * 128 * 4);
    float* p     = (float*)alloc((size_t)NG * DD * 4);
    int*   bsum  = (int*)alloc(SCAN_B * 4);
    int*   boff  = (int*)alloc(SCAN_B * 4);

    const int* srcI = ei;
    const int* dstI = ei + NE;

    hipMemsetAsync(cnt, 0, (size_t)NN * 4, stream);
    hipMemsetAsync(fc, 0, (size_t)NN * 4, stream);
    hipMemsetAsync(stats, 0, 3 * 256 * 4, stream);
    hipMemsetAsync(p, 0, (size_t)NG * DD * 4, stream);

    count_k<<<(NE + 255) / 256, 256, 0, stream>>>(dstI, cnt);
    sum_k<<<SCAN_B, 256, 0, stream>>>(cnt, bsum);
    bscan_k<<<1, 256, 0, stream>>>(bsum, boff, rs);
    cscan_k<<<SCAN_B, 256, 0, stream>>>(cnt, boff, rs, dis);
    fill_k<<<(NE + 255) / 256, 256, 0, stream>>>(srcI, dstI, rs, fc, ssrc);

    const int GB = (NN + 31) / 32;

    // Layer 1
    gemm_k<<<GB, 256, 0, stream>>>(x, W1, nullptr, nullptr, dis, hb, 0);
    gather_k<<<2048, 256, 0, stream>>>(hb, dis, rs, ssrc, b1, agg, stats);
    bnfix_k<<<1, 128, 0, stream>>>(stats, g1, be1, scb, shb);

    // Layer 2
    gemm_k<<<GB, 256, 0, stream>>>(agg, W2, scb, shb, dis, hb, 1);
    gather_k<<<2048, 256, 0, stream>>>(hb, dis, rs, ssrc, b2, agg, stats + 256);
    bnfix_k<<<1, 128, 0, stream>>>(stats + 256, g2, be2, scb + 128, shb + 128);

    // Layer 3
    gemm_k<<<GB, 256, 0, stream>>>(agg, W3, scb + 128, shb + 128, dis, hb, 1);
    gather_k<<<2048, 256, 0, stream>>>(hb, dis, rs, ssrc, b3, agg, stats + 512);
    bnfix_k<<<1, 128, 0, stream>>>(stats + 512, g3, be3, scb + 256, shb + 256);

    // Pool + head
    pool_k<<<128, 256, 0, stream>>>(agg, batch, scb + 256, shb + 256, p);
    head_k<<<NG, 128, 0, stream>>>(p, Wm1, bm1, Wm2, bm2, out);
}